// Round 6
// baseline (307.713 us; speedup 1.0000x reference)
//
#include <hip/hip_runtime.h>

typedef unsigned short u16;
typedef __attribute__((ext_vector_type(8))) short short8;   // 8 bf16 (4 VGPRs) - MFMA A/B frag
typedef __attribute__((ext_vector_type(4))) float f4;       // MFMA C/D frag
typedef __attribute__((ext_vector_type(8))) unsigned short us8;

// ---------- helpers ----------
__device__ __forceinline__ u16 f2bf(float f) {              // RNE fp32 -> bf16
    unsigned u = __float_as_uint(f);
    u += 0x7FFFu + ((u >> 16) & 1u);
    return (u16)(u >> 16);
}
__device__ __forceinline__ float bf2f(u16 h) {
    return __uint_as_float(((unsigned)h) << 16);
}

#define GLD16(gp, lp) __builtin_amdgcn_global_load_lds( \
    (const __attribute__((address_space(1))) void*)(gp), \
    (__attribute__((address_space(3))) void*)(lp), 16, 0, 0)

// s = (d_head^0.5)^(-0.25) = 8^(-0.25)
#define SCALE_S 0.594603557501360533f

// ---------- fp32 -> bf16 (8 elems/thread) ----------
__global__ __launch_bounds__(256) void convert_f32_bf16(const float* __restrict__ in,
                                                        u16* __restrict__ out) {
    const size_t i = (size_t)blockIdx.x * 256 + threadIdx.x;
    const float4* p = (const float4*)in + i * 2;
    float4 a = p[0], b = p[1];
    us8 r;
    r[0] = f2bf(a.x); r[1] = f2bf(a.y); r[2] = f2bf(a.z); r[3] = f2bf(a.w);
    r[4] = f2bf(b.x); r[5] = f2bf(b.y); r[6] = f2bf(b.z); r[7] = f2bf(b.w);
    *(us8*)(out + i * 8) = r;
}

// ---------- transpose + convert x3: out[n][k] = bf16(W[k][n]), 1024x1024 ----------
__global__ __launch_bounds__(256) void transpose_convert3(
    const float* __restrict__ Wq, const float* __restrict__ Wv, const float* __restrict__ Wo,
    u16* __restrict__ WqvT, u16* __restrict__ WoT) {
    const float* W; u16* out;
    if (blockIdx.z == 0)      { W = Wq; out = WqvT; }
    else if (blockIdx.z == 1) { W = Wv; out = WqvT + 1024 * 1024; }
    else                      { W = Wo; out = WoT; }
    __shared__ float tile[32][33];
    const int tx = threadIdx.x, ty = threadIdx.y;   // 32 x 8
    const int x = blockIdx.x * 32 + tx;
#pragma unroll
    for (int i = 0; i < 4; ++i) {
        const int y = blockIdx.y * 32 + ty + i * 8;
        tile[ty + i * 8][tx] = W[(size_t)y * 1024 + x];
    }
    __syncthreads();
#pragma unroll
    for (int i = 0; i < 4; ++i) {
        const int yo = blockIdx.x * 32 + ty + i * 8;  // out row (= W col)
        const int xo = blockIdx.y * 32 + tx;          // out col (= W row)
        out[(size_t)yo * 1024 + xo] = f2bf(tile[tx][ty + i * 8]);
    }
}

__global__ void concat_bias(const float* __restrict__ bq, const float* __restrict__ bv,
                            float* __restrict__ bqv) {
    const int i = blockIdx.x * 256 + threadIdx.x;   // 0..2047
    bqv[i] = (i < 1024) ? bq[i] : bv[i - 1024];
}

// ============================================================================
// 256x256 GEMM core, PIPELINED 2-cluster K-tile: at every barrier-cross the
// next MFMA cluster's operands are ALREADY resident (m201's key property).
// 3-buffer A rotation + 2-buffer B, 160 KB LDS, counted vmcnt (T4), T2
// swizzle, T5 setprio. 512 threads = 8 waves (2Mx4N), out 128x64/wave, BK=64.
//
// Steady state, tile kt (bfc = bf(kt), read during Y(kt-1)):
//  X: read af0,af1(kt) [16 ds_read from As[kt%3]]
//     stage A(kt+2)->As[(kt+2)%3]
//     WAITV(4): in-flight {A(kt+1),B(kt+1),A(kt+2)}=12 -> drains A/B(kt+1)
//               (issued 1-1.5 tiles ago; ~free), leaves A(kt+2)
//     MFMA c1 = bfc x af0 (af0 ~150cyc exposure, covered by co-wave)
//     B1 -- publishes A(kt+1),B(kt+1) (all waves drained them pre-B1)
//  Y: read bf(kt+1) [8 ds_read from Bs[(kt+1)%2]]  <- legal: published at B1
//     stage B(kt+2)->Bs[kt%2]  (bf(kt) readers retired in-order pre-B1)
//     MFMA c2 = bfc x af1 (af1 read a segment ago: fully hidden)
//     B2; bfc = bf(kt+1)
// Slot hazards: A-slot overwrite (X(kt)) is >=1 barrier after tile kt-1's
// af reads retired (pre-B2(kt-1)); B-slot overwrite (Y(kt)) after B1(kt)
// with bf(kt) reads retired pre-B1 (in-order lgkm). Tail: kt14 WAITV(0)+no
// stages; kt15 barrier-free. Regs: acc128+bfc32+af64+addr ~= 240 <= 256.
// MFMA operands SWAPPED (mfma(b,a,acc)): lane's 4 acc regs = 4 consecutive
// output COLUMNS (row = lrow) -> coalesced uint2/float4 epilogue stores.
// ============================================================================
#define BAR8() do { asm volatile("" ::: "memory"); __builtin_amdgcn_s_barrier(); \
                    asm volatile("" ::: "memory"); } while (0)
#define WAITV(n) asm volatile("s_waitcnt vmcnt(" #n ")" ::: "memory")

// p = per-thread global src ptr (row lr0, swizzled col, advanced by caller)
#define STG2(arr, p, half) do { \
    const u16* s_ = (p) + (size_t)(half) * 128 * 1024; \
    u16* d_ = &arr[half][ldst]; \
    GLD16(s_, d_); \
    GLD16(s_ + (size_t)64 * 1024, d_ + 64 * 64); \
} while (0)

#define RD_AF(af, AsR, roff) \
    _Pragma("unroll") for (int i_ = 0; i_ < 4; ++i_) \
    _Pragma("unroll") for (int kk_ = 0; kk_ < 2; ++kk_) \
        af[i_][kk_] = *(const short8*)&AsR[wrow][((roff) + i_ * 16 + lrow) * 64 + (kg0 ^ (kk_ << 5))];

#define RD_BF(bfa, BsX) \
    _Pragma("unroll") for (int j_ = 0; j_ < 4; ++j_) \
    _Pragma("unroll") for (int kk_ = 0; kk_ < 2; ++kk_) \
        bfa[j_][kk_] = *(const short8*)&BsX[bhalf][(brow + j_ * 16 + lrow) * 64 + (kg0 ^ (kk_ << 5))];

#define MFMA_C(base, bfa, afa) \
    _Pragma("unroll") for (int kk_ = 0; kk_ < 2; ++kk_) \
    _Pragma("unroll") for (int i_ = 0; i_ < 4; ++i_) \
    _Pragma("unroll") for (int j_ = 0; j_ < 4; ++j_) \
        acc[(base) + i_][j_] = __builtin_amdgcn_mfma_f32_16x16x32_bf16( \
            bfa[j_][kk_], afa[i_][kk_], acc[(base) + i_][j_], 0, 0, 0);

#define KTILE_D(AsR, BsN, AsW, BsW) do { \
    short8 af0[4][2], af1[4][2]; \
    RD_AF(af0, AsR, 0) \
    RD_AF(af1, AsR, 64) \
    STG2(AsW, aP, 0); STG2(AsW, aP, 1); aP += 64; \
    WAITV(4); \
    __builtin_amdgcn_s_setprio(1); MFMA_C(0, bfc, af0) __builtin_amdgcn_s_setprio(0); \
    BAR8(); \
    short8 bfn[4][2]; \
    RD_BF(bfn, BsN) \
    STG2(BsW, bP, 0); STG2(BsW, bP, 1); bP += 64; \
    __builtin_amdgcn_s_setprio(1); MFMA_C(4, bfc, af1) __builtin_amdgcn_s_setprio(0); \
    BAR8(); \
    _Pragma("unroll") for (int j_ = 0; j_ < 4; ++j_) \
    _Pragma("unroll") for (int kk_ = 0; kk_ < 2; ++kk_) \
        bfc[j_][kk_] = bfn[j_][kk_]; \
} while (0)

#define GEMM_PRO_AND_LOOP() \
    STG2(As0, aS, 0); STG2(As0, aS, 1); \
    STG2(Bs0, bS, 0); STG2(Bs0, bS, 1); \
    { const u16* a1 = aS + 64; STG2(As1, a1, 0); STG2(As1, a1, 1); } \
    { const u16* b1 = bS + 64; STG2(Bs1, b1, 0); STG2(Bs1, b1, 1); } \
    WAITV(8); \
    BAR8(); \
    short8 bfc[4][2]; \
    RD_BF(bfc, Bs0) \
    const u16* aP = aS + 128; \
    const u16* bP = bS + 128; \
    for (int g6 = 0; g6 < 2; ++g6) { \
        KTILE_D(As0, Bs1, As2, Bs0);  /* kt=6g+0 */ \
        KTILE_D(As1, Bs0, As0, Bs1);  /* kt=6g+1 */ \
        KTILE_D(As2, Bs1, As1, Bs0);  /* kt=6g+2 */ \
        KTILE_D(As0, Bs0, As2, Bs1);  /* kt=6g+3 */ \
        KTILE_D(As1, Bs1, As0, Bs0);  /* kt=6g+4 */ \
        KTILE_D(As2, Bs0, As1, Bs1);  /* kt=6g+5 */ \
    } \
    KTILE_D(As0, Bs1, As2, Bs0);      /* kt=12: stages A(14)->As2, B(14)->Bs0 */ \
    KTILE_D(As1, Bs0, As0, Bs1);      /* kt=13: stages A(15)->As0, B(15)->Bs1 */ \
    {   /* kt=14: no stages, full drain */ \
        short8 af0[4][2], af1[4][2]; \
        RD_AF(af0, As2, 0) \
        RD_AF(af1, As2, 64) \
        WAITV(0); \
        __builtin_amdgcn_s_setprio(1); MFMA_C(0, bfc, af0) __builtin_amdgcn_s_setprio(0); \
        BAR8(); \
        short8 bfn[4][2]; \
        RD_BF(bfn, Bs1) \
        __builtin_amdgcn_s_setprio(1); MFMA_C(4, bfc, af1) __builtin_amdgcn_s_setprio(0); \
        _Pragma("unroll") for (int j_ = 0; j_ < 4; ++j_) \
        _Pragma("unroll") for (int kk_ = 0; kk_ < 2; ++kk_) \
            bfc[j_][kk_] = bfn[j_][kk_]; \
    } \
    {   /* kt=15: barrier-free */ \
        short8 af0[4][2], af1[4][2]; \
        RD_AF(af0, As0, 0) \
        RD_AF(af1, As0, 64) \
        MFMA_C(0, bfc, af0) \
        MFMA_C(4, bfc, af1) \
    }

// ---------- GEMM1: [x] @ [WqT;WvT]^T + bias, fused first-softmax epilogue ----------
__global__ __launch_bounds__(512, 2) void gemm_qv(
    const u16* __restrict__ A, const u16* __restrict__ BT,
    const float* __restrict__ bias,
    u16* __restrict__ qsOut, u16* __restrict__ vOut)
{
    __shared__ u16 As0[2][128 * 64], As1[2][128 * 64], As2[2][128 * 64];
    __shared__ u16 Bs0[2][128 * 64], Bs1[2][128 * 64];
    const int t = threadIdx.x;
    const int l = t & 63, w = t >> 6;
    const int quad = l >> 4, lrow = l & 15;
    const int wrow = w >> 2, wcol = w & 3;
    const int bhalf = wcol >> 1, brow = (wcol & 1) * 64;

    int bx, by;
    {
        const int id = blockIdx.x + (int)gridDim.x * blockIdx.y;
        const int xcd = id & 7, j = id >> 3;
        const int xs = (int)gridDim.x >> 3;
        bx = xcd * xs + (j % xs);
        by = j / xs;
    }
    const int m0 = bx * 256, n0 = by * 256;

    const int lr0 = t >> 3;                      // row within half (0..63)
    const int cg = ((t & 7) ^ (lr0 & 7)) * 8;    // swizzled k-granule
    const int ldst = lr0 * 64 + (t & 7) * 8;     // LDS dst = uniform + lane*16B
    const u16* aS = A  + (size_t)(m0 + lr0) * 1024 + cg;
    const u16* bS = BT + (size_t)(n0 + lr0) * 1024 + cg;

    const int kg0 = (quad ^ (lrow & 7)) << 3;
    f4 acc[8][4] = {};

    GEMM_PRO_AND_LOOP()

    // epilogue (swapped layout): row m = ... + lrow; lane's acc[i][j][r] = col
    // n0 + wcol*64 + j*16 + quad*4 + r. Head = wave's 64-col span.
    const int colh = n0 + wcol * 64;
    const bool isQ = n0 < 1024;                 // block-uniform (256-wide tiles)
    float4 bs4[4];
#pragma unroll
    for (int j = 0; j < 4; ++j)
        bs4[j] = *(const float4*)&bias[colh + j * 16 + quad * 4];

#pragma unroll
    for (int i = 0; i < 8; ++i) {
        const int m = m0 + wrow * 128 + i * 16 + lrow;
        float v[4][4];
#pragma unroll
        for (int j = 0; j < 4; ++j) {
            v[j][0] = acc[i][j][0] + bs4[j].x;
            v[j][1] = acc[i][j][1] + bs4[j].y;
            v[j][2] = acc[i][j][2] + bs4[j].z;
            v[j][3] = acc[i][j][3] + bs4[j].w;
        }
        if (isQ) {
            float mx = v[0][0];
#pragma unroll
            for (int j = 0; j < 4; ++j)
#pragma unroll
                for (int r = 0; r < 4; ++r) mx = fmaxf(mx, v[j][r]);
            mx = fmaxf(mx, __shfl_xor(mx, 16));
            mx = fmaxf(mx, __shfl_xor(mx, 32));
            float sm = 0.f;
#pragma unroll
            for (int j = 0; j < 4; ++j)
#pragma unroll
                for (int r = 0; r < 4; ++r) { v[j][r] = __expf(v[j][r] - mx); sm += v[j][r]; }
            sm += __shfl_xor(sm, 16);
            sm += __shfl_xor(sm, 32);
            const float inv = SCALE_S / sm;
            u16* qp = qsOut + (size_t)m * 1024 + colh + quad * 4;
#pragma unroll
            for (int j = 0; j < 4; ++j) {
                uint2 pk;
                pk.x = (unsigned)f2bf(v[j][0] * inv) | ((unsigned)f2bf(v[j][1] * inv) << 16);
                pk.y = (unsigned)f2bf(v[j][2] * inv) | ((unsigned)f2bf(v[j][3] * inv) << 16);
                *(uint2*)(qp + j * 16) = pk;
            }
        } else {
            u16* vp = vOut + (size_t)m * 1024 + (colh - 1024) + quad * 4;
#pragma unroll
            for (int j = 0; j < 4; ++j) {
                uint2 pk;
                pk.x = (unsigned)f2bf(v[j][0]) | ((unsigned)f2bf(v[j][1]) << 16);
                pk.y = (unsigned)f2bf(v[j][2]) | ((unsigned)f2bf(v[j][3]) << 16);
                *(uint2*)(vp + j * 16) = pk;
            }
        }
    }
}

// ---------- GEMM3: out[z] = qs[z] @ WopT[z]^T + bo (fp32 store) ----------
__global__ __launch_bounds__(512, 2) void gemm_out(
    const u16* __restrict__ A, const u16* __restrict__ BT,
    const float* __restrict__ bias, float* __restrict__ C)
{
    __shared__ u16 As0[2][128 * 64], As1[2][128 * 64], As2[2][128 * 64];
    __shared__ u16 Bs0[2][128 * 64], Bs1[2][128 * 64];
    const int t = threadIdx.x;
    const int l = t & 63, w = t >> 6;
    const int quad = l >> 4, lrow = l & 15;
    const int wrow = w >> 2, wcol = w & 3;
    const int bhalf = wcol >> 1, brow = (wcol & 1) * 64;
    const int z = blockIdx.z;
    A  += (size_t)z * (4096 * 1024);
    BT += (size_t)z * (1024 * 1024);
    C  += (size_t)z * (4096 * 1024);

    int bx, by;
    {
        const int id = blockIdx.x + (int)gridDim.x * blockIdx.y;
        const int xcd = id & 7, j = id >> 3;
        const int xs = (int)gridDim.x >> 3;    // 2
        bx = xcd * xs + (j % xs);
        by = j / xs;
    }
    const int m0 = bx * 256, n0 = by * 256;

    const int lr0 = t >> 3;
    const int cg = ((t & 7) ^ (lr0 & 7)) * 8;
    const int ldst = lr0 * 64 + (t & 7) * 8;
    const u16* aS = A  + (size_t)(m0 + lr0) * 1024 + cg;
    const u16* bS = BT + (size_t)(n0 + lr0) * 1024 + cg;

    const int kg0 = (quad ^ (lrow & 7)) << 3;
    f4 acc[8][4] = {};

    GEMM_PRO_AND_LOOP()

    // epilogue (swapped layout): float4 coalesced stores
    const int colh = n0 + wcol * 64;
    float4 bs4[4];
#pragma unroll
    for (int j = 0; j < 4; ++j)
        bs4[j] = *(const float4*)&bias[colh + j * 16 + quad * 4];
#pragma unroll
    for (int i = 0; i < 8; ++i) {
        const int m = m0 + wrow * 128 + i * 16 + lrow;
        float* cp = C + (size_t)m * 1024 + colh + quad * 4;
#pragma unroll
        for (int j = 0; j < 4; ++j) {
            float4 o;
            o.x = acc[i][j][0] + bs4[j].x;
            o.y = acc[i][j][1] + bs4[j].y;
            o.z = acc[i][j][2] + bs4[j].z;
            o.w = acc[i][j][3] + bs4[j].w;
            *(float4*)(cp + j * 16) = o;
        }
    }
}

// ---------- ctx partials via MFMA: Mpart[split][g][d][e] = sum_n exp(qs[n,d]) * v[n,e] ----
__global__ __launch_bounds__(256) void ctx_mfma(
    const u16* __restrict__ qs, const u16* __restrict__ vb,
    float* __restrict__ Mpart, float* __restrict__ Zpart)
{
    __shared__ __align__(16) u16 Et[2][64 * 64];
    __shared__ __align__(16) u16 Vt[2][64 * 64];
    const int t = threadIdx.x;
    const int w = t >> 6, l = t & 63;
    const int quad = l >> 4, lrow = l & 15;
    const int g = blockIdx.x;          // b = g>>4, h = g&15
    const int split = blockIdx.y;      // 0..15
    const int b = g >> 4, h = g & 15;

    const int n0 = (l & 31) * 2;       // rows n0, n0+1 within slab
    const int d0 = w * 16 + (l >> 5) * 8;
    const u16* qp = qs + ((size_t)b * 4096 + (size_t)split * 256 + n0) * 1024 + h * 64 + d0;
    const u16* vp = vb + ((size_t)b * 4096 + (size_t)split * 256 + n0) * 1024 + h * 64 + d0;

    f4 acc[4] = {};
    float zacc[8] = {};

    us8 q8a = *(const us8*)qp;
    us8 q8b = *(const us8*)(qp + 1024);
    us8 v8a = *(const us8*)vp;
    us8 v8b = *(const us8*)(vp + 1024);

    for (int slab = 0; slab < 4; ++slab) {
        unsigned epk[8], vpk[8];
#pragma unroll
        for (int j = 0; j < 8; ++j) {
            float ea = __expf(bf2f((u16)q8a[j]));
            float eb = __expf(bf2f((u16)q8b[j]));
            zacc[j] += ea + eb;
            epk[j] = (unsigned)f2bf(ea) | ((unsigned)f2bf(eb) << 16);
            vpk[j] = (unsigned)(u16)v8a[j] | ((unsigned)(u16)v8b[j] << 16);
        }
        if (slab < 3) {                // prefetch next slab (overlaps sync+MFMA below)
            qp += 64 * 1024; vp += 64 * 1024;
            q8a = *(const us8*)qp;  q8b = *(const us8*)(qp + 1024);
            v8a = *(const us8*)vp;  v8b = *(const us8*)(vp + 1024);
        }
        u16* et = Et[slab & 1];
        u16* vt = Vt[slab & 1];
#pragma unroll
        for (int j = 0; j < 8; ++j) {
            const int d = d0 + j;
            const int off = d * 64 + (((n0 >> 3) ^ (d & 7)) << 3) + (n0 & 7);
            *(unsigned*)&et[off] = epk[j];
            *(unsigned*)&vt[off] = vpk[j];
        }
        __syncthreads();
#pragma unroll
        for (int kk = 0; kk < 2; ++kk) {
            const int blk = ((kk * 4 + quad) ^ (lrow & 7)) << 3;
            short8 a = *(const short8*)&et[(w * 16 + lrow) * 64 + blk];
#pragma unroll
            for (int j = 0; j < 4; ++j) {
                short8 bfr = *(const short8*)&vt[(j * 16 + lrow) * 64 + blk];
                acc[j] = __builtin_amdgcn_mfma_f32_16x16x32_bf16(bfr, a, acc[j], 0, 0, 0);
            }
        }
    }

    // Z: butterfly within each 32-lane half (all lanes of a half share d0-range)
#pragma unroll
    for (int j = 0; j < 8; ++j) {
        zacc[j] += __shfl_xor(zacc[j], 1);
        zacc[j] += __shfl_xor(zacc[j], 2);
        zacc[j] += __shfl_xor(zacc[j], 4);
        zacc[j] += __shfl_xor(zacc[j], 8);
        zacc[j] += __shfl_xor(zacc[j], 16);
    }
    if ((l & 31) == 0) {
        float* zp = Zpart + ((size_t)split * 64 + g) * 64 + d0;
#pragma unroll
        for (int j = 0; j < 8; ++j) zp[j] = zacc[j];
    }

    // store acc (swapped layout): d = w*16 + lrow, e = j*16 + quad*4 + r -> float4
    float* mp = Mpart + ((size_t)split * 64 + g) * 4096;
#pragma unroll
    for (int j = 0; j < 4; ++j) {
        float4 o;
        o.x = acc[j][0]; o.y = acc[j][1]; o.z = acc[j][2]; o.w = acc[j][3];
        *(float4*)&mp[(w * 16 + lrow) * 64 + j * 16 + quad * 4] = o;
    }
}

// ---------- reduce partials + normalize: ctx2[g][d][e] = s * sum M / sum Z ----------
// 256 blocks (4 per g): quarter q handles idx in [q*1024, (q+1)*1024)
__global__ __launch_bounds__(256) void ctx_norm(const float* __restrict__ Mpart,
                                                const float* __restrict__ Zpart,
                                                float* __restrict__ ctx2) {
    const int g = blockIdx.x >> 2, q = blockIdx.x & 3, t = threadIdx.x;
    __shared__ float rz[64];
    if (t < 64) {
        float zsum = 0.f;
#pragma unroll
        for (int s = 0; s < 16; ++s) zsum += Zpart[((size_t)s * 64 + g) * 64 + t];
        rz[t] = SCALE_S / zsum;
    }
    __syncthreads();
    const int base = q * 1024;
    for (int ii = t; ii < 1024; ii += 256) {
        const int idx = base + ii;
        float m = 0.f;
#pragma unroll
        for (int s = 0; s < 16; ++s) m += Mpart[((size_t)s * 64 + g) * 4096 + idx];
        ctx2[(size_t)g * 4096 + idx] = m * rz[idx >> 6];
    }
}

// ---------- W'T_b[j][h*64+d] = sum_e WoT[j][h*64+e] * ctx2[b,h][d][e] ----------
__global__ __launch_bounds__(256) void woprime(const float* __restrict__ ctx2,
                                               const u16* __restrict__ WoT,
                                               u16* __restrict__ WopT) {
    __shared__ float ctxT[64 * 65];          // [e][d], padded
    __shared__ __align__(16) u16 wo[64 * 64];
    const int t = threadIdx.x;
    const int jt = blockIdx.x, h = blockIdx.y, b = blockIdx.z;
    const int g = b * 16 + h;
    for (int idx = t; idx < 4096; idx += 256) {
        const int d = idx >> 6, e = idx & 63;
        ctxT[e * 65 + d] = ctx2[(size_t)g * 4096 + idx];
    }
    const int j0 = jt * 64;
#pragma unroll
    for (int c = 0; c < 2; ++c) {
        const int ii = c * 256 + t;
        const int j = ii >> 3, c8 = ii & 7;
        *(us8*)&wo[j * 64 + c8 * 8] = *(const us8*)&WoT[(size_t)(j0 + j) * 1024 + h * 64 + c8 * 8];
    }
    __syncthreads();
    const int d = t & 63, w = t >> 6;
    float accj[16] = {};
    for (int eb = 0; eb < 8; ++eb) {
        float c8[8];
#pragma unroll
        for (int e = 0; e < 8; ++e) c8[e] = ctxT[(eb * 8 + e) * 65 + d];
#pragma unroll
        for (int jj = 0; jj < 16; ++jj) {
            us8 w8 = *(const us8*)&wo[(jj * 4 + w) * 64 + eb * 8];   // wave-uniform broadcast
#pragma unroll
            for (int e = 0; e < 8; ++e)
                accj[jj] += bf2f((u16)w8[e]) * c8[e];
        }
    }
#pragma unroll
    for (int jj = 0; jj < 16; ++jj)
        WopT[(size_t)b * 1048576 + (size_t)(j0 + jj * 4 + w) * 1024 + h * 64 + d] = f2bf(accj[jj]);
}

// ---------- launch ----------
extern "C" void kernel_launch(void* const* d_in, const int* in_sizes, int n_in,
                              void* d_out, int out_size, void* d_ws, size_t ws_size,
                              hipStream_t stream)
{
    const float* x  = (const float*)d_in[0];
    const float* Wq = (const float*)d_in[1];
    const float* bq = (const float*)d_in[2];
    // d_in[3]=Wk, d_in[4]=bk : dead code in the reference, skipped
    const float* Wv = (const float*)d_in[5];
    const float* bv = (const float*)d_in[6];
    const float* Wo = (const float*)d_in[7];
    const float* bo = (const float*)d_in[8];
    float* out = (float*)d_out;

    char* ws = (char*)d_ws;
    size_t o = 0;
    auto alloc = [&](size_t bytes) { char* p = ws + o; o = (o + bytes + 255) & ~(size_t)255; return p; };
    u16*   x_bf  = (u16*)  alloc(16384ull * 1024 * 2);   // 32 MB (dead after GEMM1 -> reused as Mpart)
    u16*   WqvT  = (u16*)  alloc(2048ull * 1024 * 2);    //  4 MB
    u16*   WoT   = (u16*)  alloc(1024ull * 1024 * 2);    //  2 MB
    float* bqv   = (float*)alloc(2048ull * 4);
    u16*   qs    = (u16*)  alloc(16384ull * 1024 * 2);   // 32 MB
    u16*   vbuf  = (u16*)  alloc(16384ull * 1024 * 2);   // 32 MB
    float* Zpart = (float*)alloc(16ull * 64 * 64 * 4);
    float* ctx2  = (float*)alloc(64ull * 4096 * 4);      //  1 MB
    u16*   WopT  = (u16*)  alloc(4ull * 1024 * 1024 * 2);//  8 MB
    float* Mpart = (float*)x_bf;                         // 16 MB alias (x_bf dead by then)
    (void)ws_size; (void)in_sizes; (void)n_in; (void)out_size;

    convert_f32_bf16<<<8192, 256, 0, stream>>>(x, x_bf);
    transpose_convert3<<<dim3(32, 32, 3), dim3(32, 8), 0, stream>>>(Wq, Wv, Wo, WqvT, WoT);
    concat_bias<<<8, 256, 0, stream>>>(bq, bv, bqv);

    // QV projection + fused first softmax epilogue (256x256, pipelined reads)
    gemm_qv<<<dim3(64, 8), 512, 0, stream>>>(x_bf, WqvT, bqv, qs, vbuf);
    // second softmax (over seq) folded into MFMA-based weighted-sum partials
    ctx_mfma<<<dim3(64, 16), 256, 0, stream>>>(qs, vbuf, Mpart, Zpart);
    ctx_norm<<<256, 256, 0, stream>>>(Mpart, Zpart, ctx2);
    // W'_b = blockdiag(ctx2_b) @ Wo
    woprime<<<dim3(16, 16, 4), 256, 0, stream>>>(ctx2, WoT, WopT);
    // out = qs @ W'_b + bo (256x256, pipelined reads)
    gemm_out<<<dim3(16, 4, 4), 512, 0, stream>>>(qs, WopT, bo, out);
}

// Round 7
// 295.123 us; speedup vs baseline: 1.0427x; 1.0427x over previous
//
#include <hip/hip_runtime.h>

typedef unsigned short u16;
typedef __attribute__((ext_vector_type(8))) short short8;   // 8 bf16 (4 VGPRs) - MFMA A/B frag
typedef __attribute__((ext_vector_type(4))) float f4;       // MFMA C/D frag
typedef __attribute__((ext_vector_type(8))) unsigned short us8;

// ---------- helpers ----------
__device__ __forceinline__ u16 f2bf(float f) {              // RNE fp32 -> bf16
    unsigned u = __float_as_uint(f);
    u += 0x7FFFu + ((u >> 16) & 1u);
    return (u16)(u >> 16);
}
__device__ __forceinline__ float bf2f(u16 h) {
    return __uint_as_float(((unsigned)h) << 16);
}

#define GLD16(gp, lp) __builtin_amdgcn_global_load_lds( \
    (const __attribute__((address_space(1))) void*)(gp), \
    (__attribute__((address_space(3))) void*)(lp), 16, 0, 0)

// s = (d_head^0.5)^(-0.25) = 8^(-0.25)
#define SCALE_S 0.594603557501360533f

// ---------- fused prep: fp32->bf16 convert (x) + transpose-convert x3 (weights) ----------
// blocks [0,8192): convert x (8 elems/thread). blocks [8192,11264): weight transpose.
__global__ __launch_bounds__(256) void prep(
    const float* __restrict__ x, u16* __restrict__ x_bf,
    const float* __restrict__ Wq, const float* __restrict__ Wv, const float* __restrict__ Wo,
    u16* __restrict__ WqvT, u16* __restrict__ WoT)
{
    const int t = threadIdx.x;
    if (blockIdx.x < 8192) {
        const size_t i = (size_t)blockIdx.x * 256 + t;
        const float4* p = (const float4*)x + i * 2;
        float4 a = p[0], b = p[1];
        us8 r;
        r[0] = f2bf(a.x); r[1] = f2bf(a.y); r[2] = f2bf(a.z); r[3] = f2bf(a.w);
        r[4] = f2bf(b.x); r[5] = f2bf(b.y); r[6] = f2bf(b.z); r[7] = f2bf(b.w);
        *(us8*)(x_bf + i * 8) = r;
        return;
    }
    const int r = blockIdx.x - 8192;
    const int z = r >> 10;                 // 0..2
    const int r10 = r & 1023;
    const int bx = r10 & 31, by = r10 >> 5;
    const float* W; u16* out;
    if (z == 0)      { W = Wq; out = WqvT; }
    else if (z == 1) { W = Wv; out = WqvT + 1024 * 1024; }
    else             { W = Wo; out = WoT; }
    __shared__ float tile[32][33];
    const int tx = t & 31, ty = t >> 5;    // 32 x 8
    const int xcol = bx * 32 + tx;
#pragma unroll
    for (int i = 0; i < 4; ++i) {
        const int y = by * 32 + ty + i * 8;
        tile[ty + i * 8][tx] = W[(size_t)y * 1024 + xcol];
    }
    __syncthreads();
#pragma unroll
    for (int i = 0; i < 4; ++i) {
        const int yo = bx * 32 + ty + i * 8;  // out row (= W col)
        const int xo = by * 32 + tx;          // out col (= W row)
        out[(size_t)yo * 1024 + xo] = f2bf(tile[tx][ty + i * 8]);
    }
}

// ============================================================================
// 256x256 GEMM core, 2-cluster K-tile, DEEP prefetch (2 K-tiles ahead) via
// 3-buffer A rotation + 2-buffer B, 160 KB LDS. Counted vmcnt(8) (T4),
// static buffers (no runtime dbuf index), T2 swizzle, T5 setprio.
// 512 threads = 8 waves (2M x 4N), per-wave out 128x64, BK=64.
// (R5 schedule: best measured, no spills. R6's operand-carry variant spilled
//  ~25MB scratch/dispatch -> reverted.)
//
// Tile kt reads As[kt%3], Bs[kt%2]; stages A(kt+2)->As[(kt+2)%3] (cluster 1)
// and B(kt+2)->Bs[kt%2] (cluster 2, after MID-BAR).
// Hazards:
//   A-slot: As[(kt+2)%3] last read at tile kt-1 (reads retired before kt-1's
//     MFMAs -> before kt-1's END-BAR); overwrite issued after that barrier. OK
//   B-slot: Bs[kt%2] read as bf at tile-kt start, retired by cluster-1 MFMA
//     lgkm before MID-BAR; overwrite issued after MID-BAR. OK
//   WAITV(8) at tile end: FIFO in-flight = {A(kt+1),B(kt+1)} (from tile kt-1)
//     + {A(kt+2),B(kt+2)} (this tile) = 16 -> drains kt+1's 8, leaves 8.
//     Every load has a FULL K-tile (~6000 cyc) from issue to demand.
// Tail: tiles 12,13 stage A/B(14),A/B(15); then vmcnt(0), bar, 2 sync-free
// tiles (14: As2/Bs0, 15: As0/Bs1).
// MFMA operands SWAPPED (mfma(b, a, acc)): lane's 4 acc regs = 4 consecutive
// output COLUMNS (row = lrow) -> coalesced uint2/float4 epilogue stores.
// ============================================================================
#define BAR8() do { asm volatile("" ::: "memory"); __builtin_amdgcn_s_barrier(); \
                    asm volatile("" ::: "memory"); } while (0)
#define WAITV(n) asm volatile("s_waitcnt vmcnt(" #n ")" ::: "memory")

// p = per-thread global src ptr (row lr0, swizzled col, advanced by caller)
#define STG2(arr, p, half) do { \
    const u16* s_ = (p) + (size_t)(half) * 128 * 1024; \
    u16* d_ = &arr[half][ldst]; \
    GLD16(s_, d_); \
    GLD16(s_ + (size_t)64 * 1024, d_ + 64 * 64); \
} while (0)

#define MFMA_CL(base) \
    _Pragma("unroll") for (int kk_ = 0; kk_ < 2; ++kk_) \
    _Pragma("unroll") for (int i_ = 0; i_ < 4; ++i_) \
    _Pragma("unroll") for (int j_ = 0; j_ < 4; ++j_) \
        acc[(base) + i_][j_] = __builtin_amdgcn_mfma_f32_16x16x32_bf16( \
            bf[j_][kk_], af[i_][kk_], acc[(base) + i_][j_], 0, 0, 0);

#define KTILE3(AsR, BsR, AsW, BsW) do { \
    short8 bf[4][2]; \
    _Pragma("unroll") for (int j_ = 0; j_ < 4; ++j_) \
    _Pragma("unroll") for (int kk_ = 0; kk_ < 2; ++kk_) \
        bf[j_][kk_] = *(const short8*)&BsR[bhalf][(brow + j_ * 16 + lrow) * 64 + (kg0 ^ (kk_ << 5))]; \
    { \
        short8 af[4][2]; \
        _Pragma("unroll") for (int i_ = 0; i_ < 4; ++i_) \
        _Pragma("unroll") for (int kk_ = 0; kk_ < 2; ++kk_) \
            af[i_][kk_] = *(const short8*)&AsR[wrow][(i_ * 16 + lrow) * 64 + (kg0 ^ (kk_ << 5))]; \
        STG2(AsW, aP, 0); STG2(AsW, aP, 1); aP += 64; \
        __builtin_amdgcn_s_setprio(1); \
        MFMA_CL(0) \
        __builtin_amdgcn_s_setprio(0); \
    } \
    { \
        short8 af[4][2]; \
        _Pragma("unroll") for (int i_ = 0; i_ < 4; ++i_) \
        _Pragma("unroll") for (int kk_ = 0; kk_ < 2; ++kk_) \
            af[i_][kk_] = *(const short8*)&AsR[wrow][((64 + i_ * 16 + lrow)) * 64 + (kg0 ^ (kk_ << 5))]; \
        BAR8(); \
        STG2(BsW, bP, 0); STG2(BsW, bP, 1); bP += 64; \
        __builtin_amdgcn_s_setprio(1); \
        MFMA_CL(4) \
        __builtin_amdgcn_s_setprio(0); \
    } \
    WAITV(8); \
    BAR8(); \
} while (0)

// tail K-tile: no staging, no barriers (all data resident, no writes)
#define KTILE_NOSYNC(AsR, BsR) do { \
    short8 bf[4][2]; \
    _Pragma("unroll") for (int j_ = 0; j_ < 4; ++j_) \
    _Pragma("unroll") for (int kk_ = 0; kk_ < 2; ++kk_) \
        bf[j_][kk_] = *(const short8*)&BsR[bhalf][(brow + j_ * 16 + lrow) * 64 + (kg0 ^ (kk_ << 5))]; \
    _Pragma("unroll") for (int h_ = 0; h_ < 2; ++h_) { \
        short8 af[4][2]; \
        _Pragma("unroll") for (int i_ = 0; i_ < 4; ++i_) \
        _Pragma("unroll") for (int kk_ = 0; kk_ < 2; ++kk_) \
            af[i_][kk_] = *(const short8*)&AsR[wrow][((h_ * 64 + i_ * 16 + lrow)) * 64 + (kg0 ^ (kk_ << 5))]; \
        if (h_ == 0) { MFMA_CL(0) } else { MFMA_CL(4) } \
    } \
} while (0)

#define GEMM_PRO_AND_LOOP() \
    STG2(Bs0, bS, 0); STG2(Bs0, bS, 1); \
    STG2(As0, aS, 0); STG2(As0, aS, 1); \
    { const u16* b1 = bS + 64; STG2(Bs1, b1, 0); STG2(Bs1, b1, 1); } \
    { const u16* a1 = aS + 64; STG2(As1, a1, 0); STG2(As1, a1, 1); } \
    WAITV(8); \
    BAR8(); \
    const u16* aP = aS + 128; \
    const u16* bP = bS + 128; \
    for (int it6 = 0; it6 < 2; ++it6) { \
        KTILE3(As0, Bs0, As2, Bs0); \
        KTILE3(As1, Bs1, As0, Bs1); \
        KTILE3(As2, Bs0, As1, Bs0); \
        KTILE3(As0, Bs1, As2, Bs1); \
        KTILE3(As1, Bs0, As0, Bs0); \
        KTILE3(As2, Bs1, As1, Bs1); \
    } \
    KTILE3(As0, Bs0, As2, Bs0);  /* kt=12: stages A(14)->As2, B(14)->Bs0 */ \
    KTILE3(As1, Bs1, As0, Bs1);  /* kt=13: stages A(15)->As0, B(15)->Bs1 */ \
    WAITV(0); \
    BAR8(); \
    KTILE_NOSYNC(As2, Bs0);      /* kt=14 */ \
    KTILE_NOSYNC(As0, Bs1);      /* kt=15 */

// ---------- GEMM1: [x] @ [WqT;WvT]^T + bias, fused first-softmax epilogue ----------
__global__ __launch_bounds__(512, 2) void gemm_qv(
    const u16* __restrict__ A, const u16* __restrict__ BT,
    const float* __restrict__ bq, const float* __restrict__ bv,
    u16* __restrict__ qsOut, u16* __restrict__ vOut)
{
    __shared__ u16 As0[2][128 * 64], As1[2][128 * 64], As2[2][128 * 64];
    __shared__ u16 Bs0[2][128 * 64], Bs1[2][128 * 64];
    const int t = threadIdx.x;
    const int l = t & 63, w = t >> 6;
    const int quad = l >> 4, lrow = l & 15;
    const int wrow = w >> 2, wcol = w & 3;
    const int bhalf = wcol >> 1, brow = (wcol & 1) * 64;

    int bx, by;
    {
        const int id = blockIdx.x + (int)gridDim.x * blockIdx.y;
        const int xcd = id & 7, j = id >> 3;
        const int xs = (int)gridDim.x >> 3;
        bx = xcd * xs + (j % xs);
        by = j / xs;
    }
    const int m0 = bx * 256, n0 = by * 256;

    const int lr0 = t >> 3;                      // row within half (0..63)
    const int cg = ((t & 7) ^ (lr0 & 7)) * 8;    // swizzled k-granule
    const int ldst = lr0 * 64 + (t & 7) * 8;     // LDS dst = uniform + lane*16B
    const u16* aS = A  + (size_t)(m0 + lr0) * 1024 + cg;
    const u16* bS = BT + (size_t)(n0 + lr0) * 1024 + cg;

    const int kg0 = (quad ^ (lrow & 7)) << 3;
    f4 acc[8][4] = {};

    GEMM_PRO_AND_LOOP()

    // epilogue (swapped layout): row m = ... + lrow; lane's acc[i][j][r] = col
    // n0 + wcol*64 + j*16 + quad*4 + r. Head = wave's 64-col span.
    const int colh = n0 + wcol * 64;
    const bool isQ = n0 < 1024;                 // block-uniform (256-wide tiles)
    const float* bp = isQ ? (bq + colh) : (bv + (colh - 1024));
    float4 bs4[4];
#pragma unroll
    for (int j = 0; j < 4; ++j)
        bs4[j] = *(const float4*)&bp[j * 16 + quad * 4];

#pragma unroll
    for (int i = 0; i < 8; ++i) {
        const int m = m0 + wrow * 128 + i * 16 + lrow;
        float v[4][4];
#pragma unroll
        for (int j = 0; j < 4; ++j) {
            v[j][0] = acc[i][j][0] + bs4[j].x;
            v[j][1] = acc[i][j][1] + bs4[j].y;
            v[j][2] = acc[i][j][2] + bs4[j].z;
            v[j][3] = acc[i][j][3] + bs4[j].w;
        }
        if (isQ) {
            float mx = v[0][0];
#pragma unroll
            for (int j = 0; j < 4; ++j)
#pragma unroll
                for (int r = 0; r < 4; ++r) mx = fmaxf(mx, v[j][r]);
            mx = fmaxf(mx, __shfl_xor(mx, 16));
            mx = fmaxf(mx, __shfl_xor(mx, 32));
            float sm = 0.f;
#pragma unroll
            for (int j = 0; j < 4; ++j)
#pragma unroll
                for (int r = 0; r < 4; ++r) { v[j][r] = __expf(v[j][r] - mx); sm += v[j][r]; }
            sm += __shfl_xor(sm, 16);
            sm += __shfl_xor(sm, 32);
            const float inv = SCALE_S / sm;
            u16* qp = qsOut + (size_t)m * 1024 + colh + quad * 4;
#pragma unroll
            for (int j = 0; j < 4; ++j) {
                uint2 pk;
                pk.x = (unsigned)f2bf(v[j][0] * inv) | ((unsigned)f2bf(v[j][1] * inv) << 16);
                pk.y = (unsigned)f2bf(v[j][2] * inv) | ((unsigned)f2bf(v[j][3] * inv) << 16);
                *(uint2*)(qp + j * 16) = pk;
            }
        } else {
            u16* vp = vOut + (size_t)m * 1024 + (colh - 1024) + quad * 4;
#pragma unroll
            for (int j = 0; j < 4; ++j) {
                uint2 pk;
                pk.x = (unsigned)f2bf(v[j][0]) | ((unsigned)f2bf(v[j][1]) << 16);
                pk.y = (unsigned)f2bf(v[j][2]) | ((unsigned)f2bf(v[j][3]) << 16);
                *(uint2*)(vp + j * 16) = pk;
            }
        }
    }
}

// ---------- GEMM3: out[z] = qs[z] @ WopT[z]^T + bo (fp32 store) ----------
__global__ __launch_bounds__(512, 2) void gemm_out(
    const u16* __restrict__ A, const u16* __restrict__ BT,
    const float* __restrict__ bias, float* __restrict__ C)
{
    __shared__ u16 As0[2][128 * 64], As1[2][128 * 64], As2[2][128 * 64];
    __shared__ u16 Bs0[2][128 * 64], Bs1[2][128 * 64];
    const int t = threadIdx.x;
    const int l = t & 63, w = t >> 6;
    const int quad = l >> 4, lrow = l & 15;
    const int wrow = w >> 2, wcol = w & 3;
    const int bhalf = wcol >> 1, brow = (wcol & 1) * 64;
    const int z = blockIdx.z;
    A  += (size_t)z * (4096 * 1024);
    BT += (size_t)z * (1024 * 1024);
    C  += (size_t)z * (4096 * 1024);

    int bx, by;
    {
        const int id = blockIdx.x + (int)gridDim.x * blockIdx.y;
        const int xcd = id & 7, j = id >> 3;
        const int xs = (int)gridDim.x >> 3;    // 2
        bx = xcd * xs + (j % xs);
        by = j / xs;
    }
    const int m0 = bx * 256, n0 = by * 256;

    const int lr0 = t >> 3;
    const int cg = ((t & 7) ^ (lr0 & 7)) * 8;
    const int ldst = lr0 * 64 + (t & 7) * 8;
    const u16* aS = A  + (size_t)(m0 + lr0) * 1024 + cg;
    const u16* bS = BT + (size_t)(n0 + lr0) * 1024 + cg;

    const int kg0 = (quad ^ (lrow & 7)) << 3;
    f4 acc[8][4] = {};

    GEMM_PRO_AND_LOOP()

    // epilogue (swapped layout): float4 coalesced stores
    const int colh = n0 + wcol * 64;
    float4 bs4[4];
#pragma unroll
    for (int j = 0; j < 4; ++j)
        bs4[j] = *(const float4*)&bias[colh + j * 16 + quad * 4];
#pragma unroll
    for (int i = 0; i < 8; ++i) {
        const int m = m0 + wrow * 128 + i * 16 + lrow;
        float* cp = C + (size_t)m * 1024 + colh + quad * 4;
#pragma unroll
        for (int j = 0; j < 4; ++j) {
            float4 o;
            o.x = acc[i][j][0] + bs4[j].x;
            o.y = acc[i][j][1] + bs4[j].y;
            o.z = acc[i][j][2] + bs4[j].z;
            o.w = acc[i][j][3] + bs4[j].w;
            *(float4*)(cp + j * 16) = o;
        }
    }
}

// ---------- ctx partials via MFMA: Mpart[split][g][d][e] = sum_n exp(qs[n,d]) * v[n,e] ----
__global__ __launch_bounds__(256) void ctx_mfma(
    const u16* __restrict__ qs, const u16* __restrict__ vb,
    float* __restrict__ Mpart, float* __restrict__ Zpart)
{
    __shared__ __align__(16) u16 Et[2][64 * 64];
    __shared__ __align__(16) u16 Vt[2][64 * 64];
    const int t = threadIdx.x;
    const int w = t >> 6, l = t & 63;
    const int quad = l >> 4, lrow = l & 15;
    const int g = blockIdx.x;          // b = g>>4, h = g&15
    const int split = blockIdx.y;      // 0..15
    const int b = g >> 4, h = g & 15;

    const int n0 = (l & 31) * 2;       // rows n0, n0+1 within slab
    const int d0 = w * 16 + (l >> 5) * 8;
    const u16* qp = qs + ((size_t)b * 4096 + (size_t)split * 256 + n0) * 1024 + h * 64 + d0;
    const u16* vp = vb + ((size_t)b * 4096 + (size_t)split * 256 + n0) * 1024 + h * 64 + d0;

    f4 acc[4] = {};
    float zacc[8] = {};

    us8 q8a = *(const us8*)qp;
    us8 q8b = *(const us8*)(qp + 1024);
    us8 v8a = *(const us8*)vp;
    us8 v8b = *(const us8*)(vp + 1024);

    for (int slab = 0; slab < 4; ++slab) {
        unsigned epk[8], vpk[8];
#pragma unroll
        for (int j = 0; j < 8; ++j) {
            float ea = __expf(bf2f((u16)q8a[j]));
            float eb = __expf(bf2f((u16)q8b[j]));
            zacc[j] += ea + eb;
            epk[j] = (unsigned)f2bf(ea) | ((unsigned)f2bf(eb) << 16);
            vpk[j] = (unsigned)(u16)v8a[j] | ((unsigned)(u16)v8b[j] << 16);
        }
        if (slab < 3) {                // prefetch next slab (overlaps sync+MFMA below)
            qp += 64 * 1024; vp += 64 * 1024;
            q8a = *(const us8*)qp;  q8b = *(const us8*)(qp + 1024);
            v8a = *(const us8*)vp;  v8b = *(const us8*)(vp + 1024);
        }
        u16* et = Et[slab & 1];
        u16* vt = Vt[slab & 1];
#pragma unroll
        for (int j = 0; j < 8; ++j) {
            const int d = d0 + j;
            const int off = d * 64 + (((n0 >> 3) ^ (d & 7)) << 3) + (n0 & 7);
            *(unsigned*)&et[off] = epk[j];
            *(unsigned*)&vt[off] = vpk[j];
        }
        __syncthreads();
#pragma unroll
        for (int kk = 0; kk < 2; ++kk) {
            const int blk = ((kk * 4 + quad) ^ (lrow & 7)) << 3;
            short8 a = *(const short8*)&et[(w * 16 + lrow) * 64 + blk];
#pragma unroll
            for (int j = 0; j < 4; ++j) {
                short8 bfr = *(const short8*)&vt[(j * 16 + lrow) * 64 + blk];
                acc[j] = __builtin_amdgcn_mfma_f32_16x16x32_bf16(bfr, a, acc[j], 0, 0, 0);
            }
        }
    }

    // Z: butterfly within each 32-lane half (all lanes of a half share d0-range)
#pragma unroll
    for (int j = 0; j < 8; ++j) {
        zacc[j] += __shfl_xor(zacc[j], 1);
        zacc[j] += __shfl_xor(zacc[j], 2);
        zacc[j] += __shfl_xor(zacc[j], 4);
        zacc[j] += __shfl_xor(zacc[j], 8);
        zacc[j] += __shfl_xor(zacc[j], 16);
    }
    if ((l & 31) == 0) {
        float* zp = Zpart + ((size_t)split * 64 + g) * 64 + d0;
#pragma unroll
        for (int j = 0; j < 8; ++j) zp[j] = zacc[j];
    }

    // store acc (swapped layout): d = w*16 + lrow, e = j*16 + quad*4 + r -> float4
    float* mp = Mpart + ((size_t)split * 64 + g) * 4096;
#pragma unroll
    for (int j = 0; j < 4; ++j) {
        float4 o;
        o.x = acc[j][0]; o.y = acc[j][1]; o.z = acc[j][2]; o.w = acc[j][3];
        *(float4*)&mp[(w * 16 + lrow) * 64 + j * 16 + quad * 4] = o;
    }
}

// ---------- reduce partials + normalize: ctx2[g][d][e] = s * sum M / sum Z ----------
// 256 blocks (4 per g): quarter q handles idx in [q*1024, (q+1)*1024)
__global__ __launch_bounds__(256) void ctx_norm(const float* __restrict__ Mpart,
                                                const float* __restrict__ Zpart,
                                                float* __restrict__ ctx2) {
    const int g = blockIdx.x >> 2, q = blockIdx.x & 3, t = threadIdx.x;
    __shared__ float rz[64];
    if (t < 64) {
        float zsum = 0.f;
#pragma unroll
        for (int s = 0; s < 16; ++s) zsum += Zpart[((size_t)s * 64 + g) * 64 + t];
        rz[t] = SCALE_S / zsum;
    }
    __syncthreads();
    const int base = q * 1024;
    for (int ii = t; ii < 1024; ii += 256) {
        const int idx = base + ii;
        float m = 0.f;
#pragma unroll
        for (int s = 0; s < 16; ++s) m += Mpart[((size_t)s * 64 + g) * 4096 + idx];
        ctx2[(size_t)g * 4096 + idx] = m * rz[idx >> 6];
    }
}

// ---------- W'T_b[j][h*64+d] = sum_e WoT[j][h*64+e] * ctx2[b,h][d][e] ----------
__global__ __launch_bounds__(256) void woprime(const float* __restrict__ ctx2,
                                               const u16* __restrict__ WoT,
                                               u16* __restrict__ WopT) {
    __shared__ float ctxT[64 * 65];          // [e][d], padded
    __shared__ __align__(16) u16 wo[64 * 64];
    const int t = threadIdx.x;
    const int jt = blockIdx.x, h = blockIdx.y, b = blockIdx.z;
    const int g = b * 16 + h;
    for (int idx = t; idx < 4096; idx += 256) {
        const int d = idx >> 6, e = idx & 63;
        ctxT[e * 65 + d] = ctx2[(size_t)g * 4096 + idx];
    }
    const int j0 = jt * 64;
#pragma unroll
    for (int c = 0; c < 2; ++c) {
        const int ii = c * 256 + t;
        const int j = ii >> 3, c8 = ii & 7;
        *(us8*)&wo[j * 64 + c8 * 8] = *(const us8*)&WoT[(size_t)(j0 + j) * 1024 + h * 64 + c8 * 8];
    }
    __syncthreads();
    const int d = t & 63, w = t >> 6;
    float accj[16] = {};
    for (int eb = 0; eb < 8; ++eb) {
        float c8[8];
#pragma unroll
        for (int e = 0; e < 8; ++e) c8[e] = ctxT[(eb * 8 + e) * 65 + d];
#pragma unroll
        for (int jj = 0; jj < 16; ++jj) {
            us8 w8 = *(const us8*)&wo[(jj * 4 + w) * 64 + eb * 8];   // wave-uniform broadcast
#pragma unroll
            for (int e = 0; e < 8; ++e)
                accj[jj] += bf2f((u16)w8[e]) * c8[e];
        }
    }
#pragma unroll
    for (int jj = 0; jj < 16; ++jj)
        WopT[(size_t)b * 1048576 + (size_t)(j0 + jj * 4 + w) * 1024 + h * 64 + d] = f2bf(accj[jj]);
}

// ---------- launch ----------
extern "C" void kernel_launch(void* const* d_in, const int* in_sizes, int n_in,
                              void* d_out, int out_size, void* d_ws, size_t ws_size,
                              hipStream_t stream)
{
    const float* x  = (const float*)d_in[0];
    const float* Wq = (const float*)d_in[1];
    const float* bq = (const float*)d_in[2];
    // d_in[3]=Wk, d_in[4]=bk : dead code in the reference, skipped
    const float* Wv = (const float*)d_in[5];
    const float* bv = (const float*)d_in[6];
    const float* Wo = (const float*)d_in[7];
    const float* bo = (const float*)d_in[8];
    float* out = (float*)d_out;

    char* ws = (char*)d_ws;
    size_t o = 0;
    auto alloc = [&](size_t bytes) { char* p = ws + o; o = (o + bytes + 255) & ~(size_t)255; return p; };
    u16*   x_bf  = (u16*)  alloc(16384ull * 1024 * 2);   // 32 MB (dead after GEMM1 -> reused as Mpart)
    u16*   WqvT  = (u16*)  alloc(2048ull * 1024 * 2);    //  4 MB
    u16*   WoT   = (u16*)  alloc(1024ull * 1024 * 2);    //  2 MB
    u16*   qs    = (u16*)  alloc(16384ull * 1024 * 2);   // 32 MB
    u16*   vbuf  = (u16*)  alloc(16384ull * 1024 * 2);   // 32 MB
    float* Zpart = (float*)alloc(16ull * 64 * 64 * 4);
    float* ctx2  = (float*)alloc(64ull * 4096 * 4);      //  1 MB
    u16*   WopT  = (u16*)  alloc(4ull * 1024 * 1024 * 2);//  8 MB
    float* Mpart = (float*)x_bf;                         // 16 MB alias (x_bf dead by then)
    (void)ws_size; (void)in_sizes; (void)n_in; (void)out_size;

    // fused: x fp32->bf16 + 3 weight transposes (one launch)
    prep<<<11264, 256, 0, stream>>>(x, x_bf, Wq, Wv, Wo, WqvT, WoT);

    // QV projection + fused first softmax epilogue (256x256, deep-prefetch; bias fused)
    gemm_qv<<<dim3(64, 8), 512, 0, stream>>>(x_bf, WqvT, bq, bv, qs, vbuf);
    // second softmax (over seq) folded into MFMA-based weighted-sum partials
    ctx_mfma<<<dim3(64, 16), 256, 0, stream>>>(qs, vbuf, Mpart, Zpart);
    ctx_norm<<<256, 256, 0, stream>>>(Mpart, Zpart, ctx2);
    // W'_b = blockdiag(ctx2_b) @ Wo
    woprime<<<dim3(16, 16, 4), 256, 0, stream>>>(ctx2, WoT, WopT);
    // out = qs @ W'_b + bo (256x256, deep-prefetch)
    gemm_out<<<dim3(16, 4, 4), 512, 0, stream>>>(qs, WopT, bo, out);
}

// Round 8
// 292.620 us; speedup vs baseline: 1.0516x; 1.0086x over previous
//
#include <hip/hip_runtime.h>

typedef unsigned short u16;
typedef __attribute__((ext_vector_type(8))) short short8;   // 8 bf16 (4 VGPRs) - MFMA A/B frag
typedef __attribute__((ext_vector_type(4))) float f4;       // MFMA C/D frag
typedef __attribute__((ext_vector_type(8))) unsigned short us8;

// ---------- helpers ----------
__device__ __forceinline__ u16 f2bf(float f) {              // RNE fp32 -> bf16
    unsigned u = __float_as_uint(f);
    u += 0x7FFFu + ((u >> 16) & 1u);
    return (u16)(u >> 16);
}
__device__ __forceinline__ float bf2f(u16 h) {
    return __uint_as_float(((unsigned)h) << 16);
}

#define GLD16(gp, lp) __builtin_amdgcn_global_load_lds( \
    (const __attribute__((address_space(1))) void*)(gp), \
    (__attribute__((address_space(3))) void*)(lp), 16, 0, 0)

// s = (d_head^0.5)^(-0.25) = 8^(-0.25)
#define SCALE_S 0.594603557501360533f

// ---------- fused prep: fp32->bf16 convert (x) + transpose-convert x3 (weights) ----------
__global__ __launch_bounds__(256) void prep(
    const float* __restrict__ x, u16* __restrict__ x_bf,
    const float* __restrict__ Wq, const float* __restrict__ Wv, const float* __restrict__ Wo,
    u16* __restrict__ WqvT, u16* __restrict__ WoT)
{
    const int t = threadIdx.x;
    if (blockIdx.x < 8192) {
        const size_t i = (size_t)blockIdx.x * 256 + t;
        const float4* p = (const float4*)x + i * 2;
        float4 a = p[0], b = p[1];
        us8 r;
        r[0] = f2bf(a.x); r[1] = f2bf(a.y); r[2] = f2bf(a.z); r[3] = f2bf(a.w);
        r[4] = f2bf(b.x); r[5] = f2bf(b.y); r[6] = f2bf(b.z); r[7] = f2bf(b.w);
        *(us8*)(x_bf + i * 8) = r;
        return;
    }
    const int r = blockIdx.x - 8192;
    const int z = r >> 10;                 // 0..2
    const int r10 = r & 1023;
    const int bx = r10 & 31, by = r10 >> 5;
    const float* W; u16* out;
    if (z == 0)      { W = Wq; out = WqvT; }
    else if (z == 1) { W = Wv; out = WqvT + 1024 * 1024; }
    else             { W = Wo; out = WoT; }
    __shared__ float tile[32][33];
    const int tx = t & 31, ty = t >> 5;    // 32 x 8
    const int xcol = bx * 32 + tx;
#pragma unroll
    for (int i = 0; i < 4; ++i) {
        const int y = by * 32 + ty + i * 8;
        tile[ty + i * 8][tx] = W[(size_t)y * 1024 + xcol];
    }
    __syncthreads();
#pragma unroll
    for (int i = 0; i < 4; ++i) {
        const int yo = bx * 32 + ty + i * 8;  // out row (= W col)
        const int xo = by * 32 + tx;          // out col (= W row)
        out[(size_t)yo * 1024 + xo] = f2bf(tile[tx][ty + i * 8]);
    }
}

// ============================================================================
// 256x256 GEMM core, 2-cluster K-tile, deep prefetch (2 tiles) + CARRIED-bf:
// bf(kt+1) is read during tile kt's seg2 (after a relocated counted WAITV(8))
// so each tile's MFMA c1 starts with its B-operands already in registers and
// only 8 af0 ds_reads on the critical path. 3-buffer A + 2-buffer B, 160 KB
// LDS, static buffers, T2 swizzle, T5 setprio. 8 waves (2Mx4N), BK=64.
//
// Tile kt (bfCur = bf(kt), read during tile kt-1):
//  seg1: read af0(kt) [8 ds_read from As[kt%3]]
//        stage A(kt+2)->As[(kt+2)%3]
//        MFMA c1 = bfCur x af0
//        read af1(kt) [8 ds_read]          (pre-bar issue, hides under bar)
//  MID-BAR
//  seg2: stage B(kt+2)->Bs[kt%2]
//        WAITV(8): outstanding {A(kt+1),B(kt+1),A(kt+2),B(kt+2)}=16 ->
//                  drains A(kt+1),B(kt+1) (issued ~1 tile ago, ~free);
//                  leaves {A(kt+2),B(kt+2)}. Never 0 in the loop.
//        MFMA c2 = bfCur x af1
//        read bfNxt = bf(kt+1) from Bs[(kt+1)%2]   <- resident (just drained)
//  END-BAR
// Hazards (all >=1 barrier between overwrite-issue and last-read retirement):
//  * Bs[kt%2] overwrite (seg2) vs bf(kt) reads (tile kt-1 seg2): bf(kt) is
//    consumed by c1(kt) -> lgkm-retired in seg1, before MID-BAR. OK
//  * As[(kt+2)%3] overwrite (seg1) vs af reads of tile kt-1: retired before
//    c2(kt-1) -> before END-BAR(kt-1). OK
//  * bfNxt read vs its slot's next overwrite (tile kt+1 seg2): retired by
//    c1(kt+1) before kt+1's MID-BAR. OK
// Reg peak (during c2): acc128 + bfCur32 + af1 32 + addr ~20 = ~212 < 256.
// Tail: kt=13 leaves {A15,B15} in flight; WAITV(0), BAR, two sync-free tiles
// (kt=14 uses carried bf(14); bf(15) read between them).
// MFMA operands SWAPPED (mfma(b, a, acc)): lane's 4 acc regs = 4 consecutive
// output COLUMNS (row = lrow) -> coalesced uint2/float4 epilogue stores.
// ============================================================================
#define BAR8() do { asm volatile("" ::: "memory"); __builtin_amdgcn_s_barrier(); \
                    asm volatile("" ::: "memory"); } while (0)
#define WAITV(n) asm volatile("s_waitcnt vmcnt(" #n ")" ::: "memory")

// p = per-thread global src ptr (row lr0, swizzled col, advanced by caller)
#define STG2(arr, p, half) do { \
    const u16* s_ = (p) + (size_t)(half) * 128 * 1024; \
    u16* d_ = &arr[half][ldst]; \
    GLD16(s_, d_); \
    GLD16(s_ + (size_t)64 * 1024, d_ + 64 * 64); \
} while (0)

#define RD_AF(af, AsR, roff) \
    _Pragma("unroll") for (int i_ = 0; i_ < 4; ++i_) \
    _Pragma("unroll") for (int kk_ = 0; kk_ < 2; ++kk_) \
        af[i_][kk_] = *(const short8*)&AsR[wrow][((roff) + i_ * 16 + lrow) * 64 + (kg0 ^ (kk_ << 5))];

#define RD_BF(bfa, BsX) \
    _Pragma("unroll") for (int j_ = 0; j_ < 4; ++j_) \
    _Pragma("unroll") for (int kk_ = 0; kk_ < 2; ++kk_) \
        bfa[j_][kk_] = *(const short8*)&BsX[bhalf][(brow + j_ * 16 + lrow) * 64 + (kg0 ^ (kk_ << 5))];

#define MFMA_C(base, bfa, afa) \
    _Pragma("unroll") for (int kk_ = 0; kk_ < 2; ++kk_) \
    _Pragma("unroll") for (int i_ = 0; i_ < 4; ++i_) \
    _Pragma("unroll") for (int j_ = 0; j_ < 4; ++j_) \
        acc[(base) + i_][j_] = __builtin_amdgcn_mfma_f32_16x16x32_bf16( \
            bfa[j_][kk_], afa[i_][kk_], acc[(base) + i_][j_], 0, 0, 0);

#define KTILE_C(AsR, BsN, AsW, BsW, bfCur, bfNxt) do { \
    { \
        short8 af0[4][2]; \
        RD_AF(af0, AsR, 0) \
        STG2(AsW, aP, 0); STG2(AsW, aP, 1); aP += 64; \
        __builtin_amdgcn_s_setprio(1); \
        MFMA_C(0, bfCur, af0) \
        __builtin_amdgcn_s_setprio(0); \
    } \
    { \
        short8 af1[4][2]; \
        RD_AF(af1, AsR, 64) \
        BAR8(); \
        STG2(BsW, bP, 0); STG2(BsW, bP, 1); bP += 64; \
        WAITV(8); \
        __builtin_amdgcn_s_setprio(1); \
        MFMA_C(4, bfCur, af1) \
        __builtin_amdgcn_s_setprio(0); \
        RD_BF(bfNxt, BsN) \
        BAR8(); \
    } \
} while (0)

#define GEMM_PRO_AND_LOOP() \
    STG2(Bs0, bS, 0); STG2(Bs0, bS, 1); \
    STG2(As0, aS, 0); STG2(As0, aS, 1); \
    { const u16* b1 = bS + 64; STG2(Bs1, b1, 0); STG2(Bs1, b1, 1); } \
    { const u16* a1 = aS + 64; STG2(As1, a1, 0); STG2(As1, a1, 1); } \
    WAITV(8); \
    BAR8(); \
    short8 bfA[4][2], bfB[4][2]; \
    RD_BF(bfA, Bs0) \
    const u16* aP = aS + 128; \
    const u16* bP = bS + 128; \
    for (int g6 = 0; g6 < 2; ++g6) { \
        KTILE_C(As0, Bs1, As2, Bs0, bfA, bfB);  /* kt=6g+0 */ \
        KTILE_C(As1, Bs0, As0, Bs1, bfB, bfA);  /* kt=6g+1 */ \
        KTILE_C(As2, Bs1, As1, Bs0, bfA, bfB);  /* kt=6g+2 */ \
        KTILE_C(As0, Bs0, As2, Bs1, bfB, bfA);  /* kt=6g+3 */ \
        KTILE_C(As1, Bs1, As0, Bs0, bfA, bfB);  /* kt=6g+4 */ \
        KTILE_C(As2, Bs0, As1, Bs1, bfB, bfA);  /* kt=6g+5 */ \
    } \
    KTILE_C(As0, Bs1, As2, Bs0, bfA, bfB);      /* kt=12: stages A(14),B(14) */ \
    KTILE_C(As1, Bs0, As0, Bs1, bfB, bfA);      /* kt=13: stages A(15),B(15); reads bf(14) */ \
    WAITV(0); \
    BAR8(); \
    {   /* kt=14: all resident, carried bf(14)=bfA */ \
        short8 af0[4][2], af1[4][2]; \
        RD_AF(af0, As2, 0) \
        RD_AF(af1, As2, 64) \
        __builtin_amdgcn_s_setprio(1); \
        MFMA_C(0, bfA, af0) \
        MFMA_C(4, bfA, af1) \
        __builtin_amdgcn_s_setprio(0); \
        RD_BF(bfB, Bs1)     /* bf(15) */ \
    } \
    {   /* kt=15 */ \
        short8 af0[4][2], af1[4][2]; \
        RD_AF(af0, As0, 0) \
        RD_AF(af1, As0, 64) \
        MFMA_C(0, bfB, af0) \
        MFMA_C(4, bfB, af1) \
    }

// ---------- GEMM1: [x] @ [WqT;WvT]^T + bias, fused first-softmax epilogue ----------
__global__ __launch_bounds__(512, 2) void gemm_qv(
    const u16* __restrict__ A, const u16* __restrict__ BT,
    const float* __restrict__ bq, const float* __restrict__ bv,
    u16* __restrict__ qsOut, u16* __restrict__ vOut)
{
    __shared__ u16 As0[2][128 * 64], As1[2][128 * 64], As2[2][128 * 64];
    __shared__ u16 Bs0[2][128 * 64], Bs1[2][128 * 64];
    const int t = threadIdx.x;
    const int l = t & 63, w = t >> 6;
    const int quad = l >> 4, lrow = l & 15;
    const int wrow = w >> 2, wcol = w & 3;
    const int bhalf = wcol >> 1, brow = (wcol & 1) * 64;

    int bx, by;
    {
        const int id = blockIdx.x + (int)gridDim.x * blockIdx.y;
        const int xcd = id & 7, j = id >> 3;
        const int xs = (int)gridDim.x >> 3;
        bx = xcd * xs + (j % xs);
        by = j / xs;
    }
    const int m0 = bx * 256, n0 = by * 256;

    const int lr0 = t >> 3;                      // row within half (0..63)
    const int cg = ((t & 7) ^ (lr0 & 7)) * 8;    // swizzled k-granule
    const int ldst = lr0 * 64 + (t & 7) * 8;     // LDS dst = uniform + lane*16B
    const u16* aS = A  + (size_t)(m0 + lr0) * 1024 + cg;
    const u16* bS = BT + (size_t)(n0 + lr0) * 1024 + cg;

    const int kg0 = (quad ^ (lrow & 7)) << 3;
    f4 acc[8][4] = {};

    GEMM_PRO_AND_LOOP()

    // epilogue (swapped layout): row m = ... + lrow; lane's acc[i][j][r] = col
    // n0 + wcol*64 + j*16 + quad*4 + r. Head = wave's 64-col span.
    const int colh = n0 + wcol * 64;
    const bool isQ = n0 < 1024;                 // block-uniform (256-wide tiles)
    const float* bp = isQ ? (bq + colh) : (bv + (colh - 1024));
    float4 bs4[4];
#pragma unroll
    for (int j = 0; j < 4; ++j)
        bs4[j] = *(const float4*)&bp[j * 16 + quad * 4];

#pragma unroll
    for (int i = 0; i < 8; ++i) {
        const int m = m0 + wrow * 128 + i * 16 + lrow;
        float v[4][4];
#pragma unroll
        for (int j = 0; j < 4; ++j) {
            v[j][0] = acc[i][j][0] + bs4[j].x;
            v[j][1] = acc[i][j][1] + bs4[j].y;
            v[j][2] = acc[i][j][2] + bs4[j].z;
            v[j][3] = acc[i][j][3] + bs4[j].w;
        }
        if (isQ) {
            float mx = v[0][0];
#pragma unroll
            for (int j = 0; j < 4; ++j)
#pragma unroll
                for (int r = 0; r < 4; ++r) mx = fmaxf(mx, v[j][r]);
            mx = fmaxf(mx, __shfl_xor(mx, 16));
            mx = fmaxf(mx, __shfl_xor(mx, 32));
            float sm = 0.f;
#pragma unroll
            for (int j = 0; j < 4; ++j)
#pragma unroll
                for (int r = 0; r < 4; ++r) { v[j][r] = __expf(v[j][r] - mx); sm += v[j][r]; }
            sm += __shfl_xor(sm, 16);
            sm += __shfl_xor(sm, 32);
            const float inv = SCALE_S / sm;
            u16* qp = qsOut + (size_t)m * 1024 + colh + quad * 4;
#pragma unroll
            for (int j = 0; j < 4; ++j) {
                uint2 pk;
                pk.x = (unsigned)f2bf(v[j][0] * inv) | ((unsigned)f2bf(v[j][1] * inv) << 16);
                pk.y = (unsigned)f2bf(v[j][2] * inv) | ((unsigned)f2bf(v[j][3] * inv) << 16);
                *(uint2*)(qp + j * 16) = pk;
            }
        } else {
            u16* vp = vOut + (size_t)m * 1024 + (colh - 1024) + quad * 4;
#pragma unroll
            for (int j = 0; j < 4; ++j) {
                uint2 pk;
                pk.x = (unsigned)f2bf(v[j][0]) | ((unsigned)f2bf(v[j][1]) << 16);
                pk.y = (unsigned)f2bf(v[j][2]) | ((unsigned)f2bf(v[j][3]) << 16);
                *(uint2*)(vp + j * 16) = pk;
            }
        }
    }
}

// ---------- GEMM3: out[z] = qs[z] @ WopT[z]^T + bo (fp32 store) ----------
__global__ __launch_bounds__(512, 2) void gemm_out(
    const u16* __restrict__ A, const u16* __restrict__ BT,
    const float* __restrict__ bias, float* __restrict__ C)
{
    __shared__ u16 As0[2][128 * 64], As1[2][128 * 64], As2[2][128 * 64];
    __shared__ u16 Bs0[2][128 * 64], Bs1[2][128 * 64];
    const int t = threadIdx.x;
    const int l = t & 63, w = t >> 6;
    const int quad = l >> 4, lrow = l & 15;
    const int wrow = w >> 2, wcol = w & 3;
    const int bhalf = wcol >> 1, brow = (wcol & 1) * 64;
    const int z = blockIdx.z;
    A  += (size_t)z * (4096 * 1024);
    BT += (size_t)z * (1024 * 1024);
    C  += (size_t)z * (4096 * 1024);

    int bx, by;
    {
        const int id = blockIdx.x + (int)gridDim.x * blockIdx.y;
        const int xcd = id & 7, j = id >> 3;
        const int xs = (int)gridDim.x >> 3;    // 2
        bx = xcd * xs + (j % xs);
        by = j / xs;
    }
    const int m0 = bx * 256, n0 = by * 256;

    const int lr0 = t >> 3;
    const int cg = ((t & 7) ^ (lr0 & 7)) * 8;
    const int ldst = lr0 * 64 + (t & 7) * 8;
    const u16* aS = A  + (size_t)(m0 + lr0) * 1024 + cg;
    const u16* bS = BT + (size_t)(n0 + lr0) * 1024 + cg;

    const int kg0 = (quad ^ (lrow & 7)) << 3;
    f4 acc[8][4] = {};

    GEMM_PRO_AND_LOOP()

    // epilogue (swapped layout): float4 coalesced stores
    const int colh = n0 + wcol * 64;
    float4 bs4[4];
#pragma unroll
    for (int j = 0; j < 4; ++j)
        bs4[j] = *(const float4*)&bias[colh + j * 16 + quad * 4];
#pragma unroll
    for (int i = 0; i < 8; ++i) {
        const int m = m0 + wrow * 128 + i * 16 + lrow;
        float* cp = C + (size_t)m * 1024 + colh + quad * 4;
#pragma unroll
        for (int j = 0; j < 4; ++j) {
            float4 o;
            o.x = acc[i][j][0] + bs4[j].x;
            o.y = acc[i][j][1] + bs4[j].y;
            o.z = acc[i][j][2] + bs4[j].z;
            o.w = acc[i][j][3] + bs4[j].w;
            *(float4*)(cp + j * 16) = o;
        }
    }
}

// ---------- ctx partials via MFMA: Mpart[split][g][d][e] = sum_n exp(qs[n,d]) * v[n,e] ----
__global__ __launch_bounds__(256) void ctx_mfma(
    const u16* __restrict__ qs, const u16* __restrict__ vb,
    float* __restrict__ Mpart, float* __restrict__ Zpart)
{
    __shared__ __align__(16) u16 Et[2][64 * 64];
    __shared__ __align__(16) u16 Vt[2][64 * 64];
    const int t = threadIdx.x;
    const int w = t >> 6, l = t & 63;
    const int quad = l >> 4, lrow = l & 15;
    const int g = blockIdx.x;          // b = g>>4, h = g&15
    const int split = blockIdx.y;      // 0..15
    const int b = g >> 4, h = g & 15;

    const int n0 = (l & 31) * 2;       // rows n0, n0+1 within slab
    const int d0 = w * 16 + (l >> 5) * 8;
    const u16* qp = qs + ((size_t)b * 4096 + (size_t)split * 256 + n0) * 1024 + h * 64 + d0;
    const u16* vp = vb + ((size_t)b * 4096 + (size_t)split * 256 + n0) * 1024 + h * 64 + d0;

    f4 acc[4] = {};
    float zacc[8] = {};

    us8 q8a = *(const us8*)qp;
    us8 q8b = *(const us8*)(qp + 1024);
    us8 v8a = *(const us8*)vp;
    us8 v8b = *(const us8*)(vp + 1024);

    for (int slab = 0; slab < 4; ++slab) {
        unsigned epk[8], vpk[8];
#pragma unroll
        for (int j = 0; j < 8; ++j) {
            float ea = __expf(bf2f((u16)q8a[j]));
            float eb = __expf(bf2f((u16)q8b[j]));
            zacc[j] += ea + eb;
            epk[j] = (unsigned)f2bf(ea) | ((unsigned)f2bf(eb) << 16);
            vpk[j] = (unsigned)(u16)v8a[j] | ((unsigned)(u16)v8b[j] << 16);
        }
        if (slab < 3) {                // prefetch next slab (overlaps sync+MFMA below)
            qp += 64 * 1024; vp += 64 * 1024;
            q8a = *(const us8*)qp;  q8b = *(const us8*)(qp + 1024);
            v8a = *(const us8*)vp;  v8b = *(const us8*)(vp + 1024);
        }
        u16* et = Et[slab & 1];
        u16* vt = Vt[slab & 1];
#pragma unroll
        for (int j = 0; j < 8; ++j) {
            const int d = d0 + j;
            const int off = d * 64 + (((n0 >> 3) ^ (d & 7)) << 3) + (n0 & 7);
            *(unsigned*)&et[off] = epk[j];
            *(unsigned*)&vt[off] = vpk[j];
        }
        __syncthreads();
#pragma unroll
        for (int kk = 0; kk < 2; ++kk) {
            const int blk = ((kk * 4 + quad) ^ (lrow & 7)) << 3;
            short8 a = *(const short8*)&et[(w * 16 + lrow) * 64 + blk];
#pragma unroll
            for (int j = 0; j < 4; ++j) {
                short8 bfr = *(const short8*)&vt[(j * 16 + lrow) * 64 + blk];
                acc[j] = __builtin_amdgcn_mfma_f32_16x16x32_bf16(bfr, a, acc[j], 0, 0, 0);
            }
        }
    }

    // Z: butterfly within each 32-lane half (all lanes of a half share d0-range)
#pragma unroll
    for (int j = 0; j < 8; ++j) {
        zacc[j] += __shfl_xor(zacc[j], 1);
        zacc[j] += __shfl_xor(zacc[j], 2);
        zacc[j] += __shfl_xor(zacc[j], 4);
        zacc[j] += __shfl_xor(zacc[j], 8);
        zacc[j] += __shfl_xor(zacc[j], 16);
    }
    if ((l & 31) == 0) {
        float* zp = Zpart + ((size_t)split * 64 + g) * 64 + d0;
#pragma unroll
        for (int j = 0; j < 8; ++j) zp[j] = zacc[j];
    }

    // store acc (swapped layout): d = w*16 + lrow, e = j*16 + quad*4 + r -> float4
    float* mp = Mpart + ((size_t)split * 64 + g) * 4096;
#pragma unroll
    for (int j = 0; j < 4; ++j) {
        float4 o;
        o.x = acc[j][0]; o.y = acc[j][1]; o.z = acc[j][2]; o.w = acc[j][3];
        *(float4*)&mp[(w * 16 + lrow) * 64 + j * 16 + quad * 4] = o;
    }
}

// ---------- reduce partials + normalize: ctx2[g][d][e] = s * sum M / sum Z ----------
// 256 blocks (4 per g): quarter q handles idx in [q*1024, (q+1)*1024)
__global__ __launch_bounds__(256) void ctx_norm(const float* __restrict__ Mpart,
                                                const float* __restrict__ Zpart,
                                                float* __restrict__ ctx2) {
    const int g = blockIdx.x >> 2, q = blockIdx.x & 3, t = threadIdx.x;
    __shared__ float rz[64];
    if (t < 64) {
        float zsum = 0.f;
#pragma unroll
        for (int s = 0; s < 16; ++s) zsum += Zpart[((size_t)s * 64 + g) * 64 + t];
        rz[t] = SCALE_S / zsum;
    }
    __syncthreads();
    const int base = q * 1024;
    for (int ii = t; ii < 1024; ii += 256) {
        const int idx = base + ii;
        float m = 0.f;
#pragma unroll
        for (int s = 0; s < 16; ++s) m += Mpart[((size_t)s * 64 + g) * 4096 + idx];
        ctx2[(size_t)g * 4096 + idx] = m * rz[idx >> 6];
    }
}

// ---------- W'T_b[j][h*64+d] = sum_e WoT[j][h*64+e] * ctx2[b,h][d][e] ----------
__global__ __launch_bounds__(256) void woprime(const float* __restrict__ ctx2,
                                               const u16* __restrict__ WoT,
                                               u16* __restrict__ WopT) {
    __shared__ float ctxT[64 * 65];          // [e][d], padded
    __shared__ __align__(16) u16 wo[64 * 64];
    const int t = threadIdx.x;
    const int jt = blockIdx.x, h = blockIdx.y, b = blockIdx.z;
    const int g = b * 16 + h;
    for (int idx = t; idx < 4096; idx += 256) {
        const int d = idx >> 6, e = idx & 63;
        ctxT[e * 65 + d] = ctx2[(size_t)g * 4096 + idx];
    }
    const int j0 = jt * 64;
#pragma unroll
    for (int c = 0; c < 2; ++c) {
        const int ii = c * 256 + t;
        const int j = ii >> 3, c8 = ii & 7;
        *(us8*)&wo[j * 64 + c8 * 8] = *(const us8*)&WoT[(size_t)(j0 + j) * 1024 + h * 64 + c8 * 8];
    }
    __syncthreads();
    const int d = t & 63, w = t >> 6;
    float accj[16] = {};
    for (int eb = 0; eb < 8; ++eb) {
        float c8[8];
#pragma unroll
        for (int e = 0; e < 8; ++e) c8[e] = ctxT[(eb * 8 + e) * 65 + d];
#pragma unroll
        for (int jj = 0; jj < 16; ++jj) {
            us8 w8 = *(const us8*)&wo[(jj * 4 + w) * 64 + eb * 8];   // wave-uniform broadcast
#pragma unroll
            for (int e = 0; e < 8; ++e)
                accj[jj] += bf2f((u16)w8[e]) * c8[e];
        }
    }
#pragma unroll
    for (int jj = 0; jj < 16; ++jj)
        WopT[(size_t)b * 1048576 + (size_t)(j0 + jj * 4 + w) * 1024 + h * 64 + d] = f2bf(accj[jj]);
}

// ---------- launch ----------
extern "C" void kernel_launch(void* const* d_in, const int* in_sizes, int n_in,
                              void* d_out, int out_size, void* d_ws, size_t ws_size,
                              hipStream_t stream)
{
    const float* x  = (const float*)d_in[0];
    const float* Wq = (const float*)d_in[1];
    const float* bq = (const float*)d_in[2];
    // d_in[3]=Wk, d_in[4]=bk : dead code in the reference, skipped
    const float* Wv = (const float*)d_in[5];
    const float* bv = (const float*)d_in[6];
    const float* Wo = (const float*)d_in[7];
    const float* bo = (const float*)d_in[8];
    float* out = (float*)d_out;

    char* ws = (char*)d_ws;
    size_t o = 0;
    auto alloc = [&](size_t bytes) { char* p = ws + o; o = (o + bytes + 255) & ~(size_t)255; return p; };
    u16*   x_bf  = (u16*)  alloc(16384ull * 1024 * 2);   // 32 MB (dead after GEMM1 -> reused as Mpart)
    u16*   WqvT  = (u16*)  alloc(2048ull * 1024 * 2);    //  4 MB
    u16*   WoT   = (u16*)  alloc(1024ull * 1024 * 2);    //  2 MB
    u16*   qs    = (u16*)  alloc(16384ull * 1024 * 2);   // 32 MB
    u16*   vbuf  = (u16*)  alloc(16384ull * 1024 * 2);   // 32 MB
    float* Zpart = (float*)alloc(16ull * 64 * 64 * 4);
    float* ctx2  = (float*)alloc(64ull * 4096 * 4);      //  1 MB
    u16*   WopT  = (u16*)  alloc(4ull * 1024 * 1024 * 2);//  8 MB
    float* Mpart = (float*)x_bf;                         // 16 MB alias (x_bf dead by then)
    (void)ws_size; (void)in_sizes; (void)n_in; (void)out_size;

    // fused: x fp32->bf16 + 3 weight transposes (one launch)
    prep<<<11264, 256, 0, stream>>>(x, x_bf, Wq, Wv, Wo, WqvT, WoT);

    // QV projection + fused first softmax epilogue (256x256, carried-bf)
    gemm_qv<<<dim3(64, 8), 512, 0, stream>>>(x_bf, WqvT, bq, bv, qs, vbuf);
    // second softmax (over seq) folded into MFMA-based weighted-sum partials
    ctx_mfma<<<dim3(64, 16), 256, 0, stream>>>(qs, vbuf, Mpart, Zpart);
    ctx_norm<<<256, 256, 0, stream>>>(Mpart, Zpart, ctx2);
    // W'_b = blockdiag(ctx2_b) @ Wo
    woprime<<<dim3(16, 16, 4), 256, 0, stream>>>(ctx2, WoT, WopT);
    // out = qs @ W'_b + bo (256x256, carried-bf)
    gemm_out<<<dim3(16, 4, 4), 512, 0, stream>>>(qs, WopT, bo, out);
}